// Round 10
// baseline (311.183 us; speedup 1.0000x reference)
//
#include <hip/hip_runtime.h>
#include <hip/hip_bf16.h>
#include <hip/hip_cooperative_groups.h>

namespace cg = cooperative_groups;

#define D 256
#define H 4
#define DPH 64
#define NLBL 9
#define SPLITK 4
#define GRID 512
#define BLK 256

typedef __attribute__((ext_vector_type(8))) __bf16 bf16x8;
typedef __attribute__((ext_vector_type(8))) unsigned short u16x8;
typedef __attribute__((ext_vector_type(4))) float f32x4;

__device__ __forceinline__ int sw_idx(int row, int col) {
  // ushort-unit index into a [R][64] bf16 LDS tile, XOR-swizzled.
  return row * 64 + (col ^ ((row & 7) << 3));
}

__device__ __forceinline__ unsigned int pk2(float a, float b) {
  unsigned int lo = (unsigned int)__builtin_bit_cast(unsigned short, (__bf16)a);
  unsigned int hi = (unsigned int)__builtin_bit_cast(unsigned short, (__bf16)b);
  return lo | (hi << 16);
}

__device__ __forceinline__ float b2f(unsigned short u) {
  return __builtin_bit_cast(float, (unsigned int)u << 16);
}

__device__ __forceinline__ bf16x8 cvt8(float4 u0, float4 u1) {
  bf16x8 r;
  r[0] = (__bf16)u0.x; r[1] = (__bf16)u0.y; r[2] = (__bf16)u0.z; r[3] = (__bf16)u0.w;
  r[4] = (__bf16)u1.x; r[5] = (__bf16)u1.y; r[6] = (__bf16)u1.z; r[7] = (__bf16)u1.w;
  return r;
}

// ---------------------------------------------------------------------------
// Shared-memory union across phases (max member 32 KB -> 2 blocks/CU fits).
// ---------------------------------------------------------------------------
struct SMemSC { int bins[2 * NLBL]; int wtot[4]; };
struct SMemAT { unsigned short ks[4096]; unsigned short vtl[4096]; unsigned short plds[8192]; };
struct SMemPL {
  int srcs[32]; float linv[32][4];
  unsigned short ct[32 * 256];
  float psum[4][32], psum2[4][32], mu_s[32], is_s[32];
};
union __align__(16) SMem {
  SMemSC sc;
  float tlds[64][65];
  SMemAT at;
  SMemPL pl;
};

struct P {
  const float *key, *value, *query;
  const int *lbl1, *lbl2;
  const float *Wq, *bq, *Wk, *bk, *Wv, *bv, *Wf, *bf_, *gamma, *beta;
  float* out;
  int N, M;
  int *cnt, *off, *pqo, *pko, *tq, *tk, *ntl, *korder, *qorder;
  __bf16 *Wqt, *Wkt, *Wvt, *Wft, *qbuf, *kbuf, *vbuf, *pctx;
  float* pstats;
  int phase_lo, phase_hi;
};

// ---------------------------------------------------------------------------
// Phase 0: jobs 0..17 stable scatter; job 18 tables; jobs 19.. W transpose.
// ---------------------------------------------------------------------------
__device__ void ph_prep(const P& p, SMem& sm, int job) {
  const int t = threadIdx.x, lane = t & 63, wave = t >> 6;

  if (job < 18) {
    const int l = job % NLBL, a = job / NLBL;
    const int n = a ? p.M : p.N;
    const int* lbl = a ? p.lbl2 : p.lbl1;
    int* order = a ? p.qorder : p.korder;

    if (t < NLBL) sm.sc.bins[t] = 0;
    __syncthreads();
    for (int chunk = 0; chunk < n; chunk += BLK) {
      int i = chunk + t;
      int lb = (i < n) ? lbl[i] : -1;
#pragma unroll
      for (int lab = 0; lab < NLBL; ++lab) {
        unsigned long long bal = __ballot(lb == lab);
        if (lane == 0 && bal) atomicAdd(&sm.sc.bins[lab], __popcll(bal));
      }
    }
    __syncthreads();
    int base = 0;
#pragma unroll
    for (int i = 0; i < NLBL; ++i) base += (i < l) ? sm.sc.bins[i] : 0;

    int pos = 0;
    for (int chunk = 0; chunk < n; chunk += BLK) {
      int i = chunk + t;
      bool flag = (i < n) && (lbl[i] == l);
      unsigned long long bal = __ballot(flag);
      int wpref = __popcll(bal & ((1ull << lane) - 1ull));
      if (lane == 0) sm.sc.wtot[wave] = __popcll(bal);
      __syncthreads();
      int prew = 0, tot = 0;
#pragma unroll
      for (int w = 0; w < 4; ++w) {
        prew += (w < wave) ? sm.sc.wtot[w] : 0;
        tot += sm.sc.wtot[w];
      }
      if (flag) order[base + pos + prew + wpref] = i;
      pos += tot;
      __syncthreads();
    }
    return;
  }

  if (job == 18) {
    if (t < 2 * NLBL) sm.sc.bins[t] = 0;
    __syncthreads();
    for (int a = 0; a < 2; ++a) {
      const int n = a ? p.M : p.N;
      const int* lbl = a ? p.lbl2 : p.lbl1;
      for (int chunk = 0; chunk < n; chunk += BLK) {
        int i = chunk + t;
        int lb = (i < n) ? lbl[i] : -1;
#pragma unroll
        for (int lab = 0; lab < NLBL; ++lab) {
          unsigned long long bal = __ballot(lb == lab);
          if (lane == 0 && bal) atomicAdd(&sm.sc.bins[a * NLBL + lab], __popcll(bal));
        }
      }
    }
    __syncthreads();
    if (t < 2 * NLBL) p.cnt[t] = sm.sc.bins[t];
    if (t == 0) {
      int a0 = 0, a1 = 0, p0 = 0, p1 = 0, t0 = 0, t1 = 0;
      for (int l = 0; l < NLBL; ++l) {
        p.off[l] = a0;      a0 += sm.sc.bins[l];
        p.off[10 + l] = a1; a1 += sm.sc.bins[NLBL + l];
        p.pko[l] = p0; p.pqo[l] = p1;
        int tkl = (sm.sc.bins[l] + 63) >> 6;
        int tql = (sm.sc.bins[NLBL + l] + 127) >> 7;
        for (int i = 0; i < tkl; ++i) { p.tk[2 * t0] = l; p.tk[2 * t0 + 1] = p0 + (i << 6); ++t0; }
        for (int i = 0; i < tql; ++i) { p.tq[2 * t1] = l; p.tq[2 * t1 + 1] = p1 + (i << 7); ++t1; }
        p0 += tkl << 6; p1 += tql << 7;
      }
      p.off[9] = a0; p.off[19] = a1; p.pko[9] = p0; p.pqo[9] = p1;
      p.ntl[0] = t1; p.ntl[1] = t0;
    }
    return;
  }

  // ---- weight transpose+cast: Wt[n][k] = bf16(W[k][n]); 256 threads
  {
    int j = job - 19;
    int m = j >> 4, sub = j & 15;
    const float* src; __bf16* dst;
    if (m < 9)       { src = p.Wq + (size_t)m * 65536;        dst = p.Wqt + (size_t)m * 65536; }
    else if (m < 18) { src = p.Wk + (size_t)(m - 9) * 65536;  dst = p.Wkt + (size_t)(m - 9) * 65536; }
    else if (m < 27) { src = p.Wv + (size_t)(m - 18) * 65536; dst = p.Wvt + (size_t)(m - 18) * 65536; }
    else             { src = p.Wf;                            dst = p.Wft; }
    int k0 = (sub >> 2) << 6, n0 = (sub & 3) << 6;
    int rr = t >> 6, c = t & 63;
#pragma unroll
    for (int i = 0; i < 16; ++i) {
      int r = i * 4 + rr;
      sm.tlds[r][c] = src[(size_t)(k0 + r) * D + n0 + c];
    }
    __syncthreads();
#pragma unroll
    for (int i = 0; i < 16; ++i) {
      int r = i * 4 + rr;
      dst[(size_t)(n0 + r) * D + k0 + c] = (__bf16)sm.tlds[c][r];
    }
  }
}

// ---------------------------------------------------------------------------
// Phase 1: label-routed input projections (MFMA bf16), 32-row x 256-col tiles.
// ---------------------------------------------------------------------------
__device__ void ph_gemm(const P& p, int y, int ti, int sub) {
  const int* tt = (y == 0) ? p.tq : p.tk;
  const float* x = (y == 0) ? p.query : (y == 1 ? p.key : p.value);
  const __bf16* W = (y == 0) ? p.Wqt : (y == 1 ? p.Wkt : p.Wvt);
  const float* bias = (y == 0) ? p.bq : (y == 1 ? p.bk : p.bv);
  const int* order = (y == 0) ? p.qorder : p.korder;
  const int* po = (y == 0) ? p.pqo : p.pko;
  __bf16* outp = (y == 0) ? p.qbuf : (y == 1 ? p.kbuf : p.vbuf);
  const float sc = (y == 0) ? 0.36067376f : 1.0f;   // 0.25 * log2(e)

  const int l = tt[2 * ti], prow0 = tt[2 * ti + 1] + sub * 32;
  const int cl = (y == 0) ? p.cnt[NLBL + l] : p.cnt[l];
  const int ooff = (y == 0) ? p.off[10 + l] : p.off[l];
  const int base = prow0 - po[l];

  const int t = threadIdx.x, w = t >> 6, lane = t & 63;
  const int lr = lane & 15, lk = lane >> 4;

  int src[2];
#pragma unroll
  for (int fi = 0; fi < 2; ++fi) {
    int ridx = base + fi * 16 + lr;
    src[fi] = (ridx < cl) ? order[ooff + ridx] : -1;
  }

  bf16x8 az;
#pragma unroll
  for (int j = 0; j < 8; ++j) az[j] = (__bf16)0.f;

  f32x4 acc[2][4];
#pragma unroll
  for (int i = 0; i < 2; ++i)
#pragma unroll
    for (int j = 0; j < 4; ++j) acc[i][j] = (f32x4){0.f, 0.f, 0.f, 0.f};

  for (int kb = 0; kb < 8; ++kb) {
    const int kbase = kb * 32 + lk * 8;
    bf16x8 a[2], b[4];
#pragma unroll
    for (int fi = 0; fi < 2; ++fi) {
      if (src[fi] >= 0) {
        const float* ap = x + (size_t)src[fi] * D + kbase;
        float4 u0 = *(const float4*)ap;
        float4 u1 = *(const float4*)(ap + 4);
        a[fi] = cvt8(u0, u1);
      } else {
        a[fi] = az;
      }
    }
#pragma unroll
    for (int fj = 0; fj < 4; ++fj) {
      int col = w * 64 + fj * 16 + lr;
      b[fj] = *(const bf16x8*)(W + (size_t)l * 65536 + (size_t)col * D + kbase);
    }
#pragma unroll
    for (int fi = 0; fi < 2; ++fi)
#pragma unroll
      for (int fj = 0; fj < 4; ++fj)
        acc[fi][fj] = __builtin_amdgcn_mfma_f32_16x16x32_bf16(a[fi], b[fj], acc[fi][fj], 0, 0, 0);
  }

#pragma unroll
  for (int fj = 0; fj < 4; ++fj) {
    int col = w * 64 + fj * 16 + lr;
    float bv_ = bias[l * D + col];
#pragma unroll
    for (int fi = 0; fi < 2; ++fi)
#pragma unroll
      for (int r = 0; r < 4; ++r) {
        int row = prow0 + fi * 16 + lk * 4 + r;
        outp[(size_t)row * D + col] = (__bf16)((acc[fi][fj][r] + bv_) * sc);
      }
  }
}

// ---------------------------------------------------------------------------
// Phase 2: split-K MFMA flash attention, 128-q tiles, no-max exp2 softmax,
// register prefetch of next K/V tile. Partials bf16 + L.
// ---------------------------------------------------------------------------
__device__ void ph_attn(const P& p, SMem& sm, int tqi, int h, int s) {
  const int l = p.tq[2 * tqi], prow0 = p.tq[2 * tqi + 1];
  const int nk = p.cnt[l];
  const int ntiles = (nk + 63) >> 6;
  const int ntsz = (ntiles + SPLITK - 1) / SPLITK;
  const int tt0 = s * ntsz;
  const int tt1 = min(ntiles, tt0 + ntsz);
  if (tt0 >= tt1) return;   // block-uniform

  const int t = threadIdx.x;
  const int w = t >> 6, lane = t & 63;
  const int lr = lane & 15, lk = lane >> 4;

  const int qbase = prow0 + w * 32;
  bf16x8 b_q[2][2];
#pragma unroll
  for (int qf = 0; qf < 2; ++qf)
#pragma unroll
    for (int kb = 0; kb < 2; ++kb)
      b_q[qf][kb] = *(const bf16x8*)(p.qbuf + (size_t)(qbase + qf * 16 + lr) * D +
                                     h * DPH + kb * 32 + lk * 8);

  f32x4 acc_o[2][4];
#pragma unroll
  for (int qf = 0; qf < 2; ++qf)
#pragma unroll
    for (int i = 0; i < 4; ++i) acc_o[qf][i] = (f32x4){0.f, 0.f, 0.f, 0.f};
  float lrun[2] = {0.f, 0.f};
  const int kb0 = p.pko[l];

  const int krow = t >> 2, kc0 = (t & 3) * 16;
  const __bf16* kptr = p.kbuf + (size_t)(kb0 + krow) * D + h * DPH + kc0;
  const int vkey2 = (t & 31) * 2, vd0 = (t >> 5) * 8;
  const __bf16* vptr = p.vbuf + (size_t)(kb0 + vkey2) * D + h * DPH + vd0;

  uint4 kreg0, kreg1;
  u16x8 vreg0, vreg1;
  auto LOADT = [&](int tt) {
    const __bf16* kp = kptr + ((size_t)tt << 6) * D;
    kreg0 = *(const uint4*)kp;
    kreg1 = *(const uint4*)(kp + 8);
    const __bf16* vp = vptr + ((size_t)tt << 6) * D;
    vreg0 = *(const u16x8*)vp;
    vreg1 = *(const u16x8*)(vp + D);
  };

  LOADT(tt0);
  for (int tt = tt0; tt < tt1; ++tt) {
    const int n0 = tt << 6;
    __syncthreads();
    *(uint4*)&sm.at.ks[sw_idx(krow, kc0)] = kreg0;
    *(uint4*)&sm.at.ks[sw_idx(krow, kc0 + 8)] = kreg1;
#pragma unroll
    for (int j = 0; j < 8; ++j) {
      unsigned int u = (unsigned int)vreg0[j] | ((unsigned int)vreg1[j] << 16);
      *(unsigned int*)&sm.at.vtl[sw_idx(vd0 + j, vkey2)] = u;
    }
    __syncthreads();
    if (tt + 1 < tt1) LOADT(tt + 1);

    // ---- S^T = K x Q^T
    f32x4 s_acc[2][4];
    const f32x4 zz = {0.f, 0.f, 0.f, 0.f};
#pragma unroll
    for (int fi = 0; fi < 4; ++fi) {
      bf16x8 a0 = *(const bf16x8*)&sm.at.ks[sw_idx(fi * 16 + lr, lk * 8)];
#pragma unroll
      for (int qf = 0; qf < 2; ++qf)
        s_acc[qf][fi] = __builtin_amdgcn_mfma_f32_16x16x32_bf16(a0, b_q[qf][0], zz, 0, 0, 0);
    }
#pragma unroll
    for (int fi = 0; fi < 4; ++fi) {
      bf16x8 a1 = *(const bf16x8*)&sm.at.ks[sw_idx(fi * 16 + lr, 32 + lk * 8)];
#pragma unroll
      for (int qf = 0; qf < 2; ++qf)
        s_acc[qf][fi] = __builtin_amdgcn_mfma_f32_16x16x32_bf16(a1, b_q[qf][1], s_acc[qf][fi], 0, 0, 0);
    }

    // ---- softmax weights (no max subtraction; bounded logits)
    float pw[2][16];
#pragma unroll
    for (int qf = 0; qf < 2; ++qf) {
      float ts = 0.f;
#pragma unroll
      for (int fi = 0; fi < 4; ++fi)
#pragma unroll
        for (int r = 0; r < 4; ++r) {
          int key = n0 + fi * 16 + lk * 4 + r;
          float pv = (key < nk) ? exp2f(s_acc[qf][fi][r]) : 0.f;
          pw[qf][fi * 4 + r] = pv;
          ts += pv;
        }
      ts += __shfl_xor(ts, 16, 64);
      ts += __shfl_xor(ts, 32, 64);
      lrun[qf] += ts;
    }

    // ---- P -> per-wave LDS
#pragma unroll
    for (int qf = 0; qf < 2; ++qf)
#pragma unroll
      for (int fi = 0; fi < 4; ++fi) {
        unsigned int w0 = pk2(pw[qf][fi * 4 + 0], pw[qf][fi * 4 + 1]);
        unsigned int w1 = pk2(pw[qf][fi * 4 + 2], pw[qf][fi * 4 + 3]);
        int idx = w * 2048 + sw_idx(qf * 16 + lr, fi * 16 + lk * 4);
        *(uint2*)&sm.at.plds[idx] = make_uint2(w0, w1);
      }

    // ---- O^T += V^T x P
#pragma unroll
    for (int kb = 0; kb < 2; ++kb) {
      bf16x8 bp[2];
#pragma unroll
      for (int qf = 0; qf < 2; ++qf)
        bp[qf] = *(const bf16x8*)&sm.at.plds[w * 2048 + sw_idx(qf * 16 + lr, kb * 32 + lk * 8)];
#pragma unroll
      for (int fi = 0; fi < 4; ++fi) {
        bf16x8 av = *(const bf16x8*)&sm.at.vtl[sw_idx(fi * 16 + lr, kb * 32 + lk * 8)];
#pragma unroll
        for (int qf = 0; qf < 2; ++qf)
          acc_o[qf][fi] = __builtin_amdgcn_mfma_f32_16x16x32_bf16(av, bp[qf], acc_o[qf][fi], 0, 0, 0);
      }
    }
  }

  // ---- write partials (bf16)
  const size_t pbase = ((size_t)tqi * H + h) * SPLITK + s;
  __bf16* pc = p.pctx + pbase * 8192;
#pragma unroll
  for (int qf = 0; qf < 2; ++qf) {
    int qloc = w * 32 + qf * 16 + lr;
#pragma unroll
    for (int fi = 0; fi < 4; ++fi) {
      uint2 u;
      u.x = pk2(acc_o[qf][fi][0], acc_o[qf][fi][1]);
      u.y = pk2(acc_o[qf][fi][2], acc_o[qf][fi][3]);
      *(uint2*)(pc + qloc * 64 + fi * 16 + lk * 4) = u;
    }
    if (lk == 0) p.pstats[pbase * 128 + qloc] = lrun[qf];
  }
}

// ---------------------------------------------------------------------------
// Phase 3: merge partials -> normalized bf16 ctx in LDS -> @Wf + bias +
// residual -> LayerNorm -> scatter to out. 32 rows per job.
// ---------------------------------------------------------------------------
__device__ void ph_proj(const P& p, SMem& sm, int tqi, int qq) {
  const int l = p.tq[2 * tqi];
  const int prow0 = p.tq[2 * tqi + 1] + qq * 32;
  const int qloc0 = qq * 32;
  const int cl = p.cnt[NLBL + l];
  const int ooff = p.off[10 + l];
  const int base = prow0 - p.pqo[l];
  const int nk = p.cnt[l];
  const int ntiles = (nk + 63) >> 6;
  const int ntsz = (ntiles + SPLITK - 1) / SPLITK;
  const int nsp = ntiles ? (ntiles + ntsz - 1) / ntsz : 0;

  const int t = threadIdx.x, w = t >> 6, lane = t & 63;
  const int lr = lane & 15, lk = lane >> 4;

  if (t < 32) {
    int ridx = base + t;
    sm.pl.srcs[t] = (ridx < cl) ? p.qorder[ooff + ridx] : -1;
  }
  if (t < 128) {
    int row = t >> 2, h = t & 3;
    float L = 0.f;
    for (int s = 0; s < nsp; ++s)
      L += p.pstats[(((size_t)tqi * H + h) * SPLITK + s) * 128 + qloc0 + row];
    sm.pl.linv[row][h] = (L > 0.f) ? (1.f / L) : 0.f;
  }
  __syncthreads();

  // ---- merge bf16 pctx across splits -> normalized bf16 in ct
  {
    int row = t >> 3, dseg = (t & 7) * 32;
    int h = dseg >> 6, d0 = dseg & 63;
    const __bf16* pb = p.pctx + (((size_t)tqi * H + h) * SPLITK) * 8192 +
                       (size_t)(qloc0 + row) * 64 + d0;
    float v[32];
#pragma unroll
    for (int j = 0; j < 32; ++j) v[j] = 0.f;
    for (int s = 0; s < nsp; ++s) {
      const __bf16* ps = pb + (size_t)s * 8192;
#pragma unroll
      for (int j4 = 0; j4 < 4; ++j4) {
        u16x8 u = *(const u16x8*)(ps + j4 * 8);
#pragma unroll
        for (int e = 0; e < 8; ++e) v[j4 * 8 + e] += b2f(u[e]);
      }
    }
    float iv = sm.pl.linv[row][h];
    int xr = (row & 7) << 3;
#pragma unroll
    for (int j = 0; j < 32; j += 2)
      *(unsigned int*)&sm.pl.ct[row * 256 + ((dseg + j) ^ xr)] = pk2(v[j] * iv, v[j + 1] * iv);
  }
  __syncthreads();

  // ---- GEMM: res = ct @ Wf
  f32x4 acc[2][4];
#pragma unroll
  for (int i = 0; i < 2; ++i)
#pragma unroll
    for (int j = 0; j < 4; ++j) acc[i][j] = (f32x4){0.f, 0.f, 0.f, 0.f};

  for (int kb = 0; kb < 8; ++kb) {
    const int kbase = kb * 32 + lk * 8;
    bf16x8 a[2], b[4];
#pragma unroll
    for (int fi = 0; fi < 2; ++fi) {
      int row = fi * 16 + lr;
      a[fi] = *(const bf16x8*)&sm.pl.ct[row * 256 + (kbase ^ ((row & 7) << 3))];
    }
#pragma unroll
    for (int fj = 0; fj < 4; ++fj) {
      int col = w * 64 + fj * 16 + lr;
      b[fj] = *(const bf16x8*)(p.Wft + (size_t)col * D + kbase);
    }
#pragma unroll
    for (int fi = 0; fi < 2; ++fi)
#pragma unroll
      for (int fj = 0; fj < 4; ++fj)
        acc[fi][fj] = __builtin_amdgcn_mfma_f32_16x16x32_bf16(a[fi], b[fj], acc[fi][fj], 0, 0, 0);
  }

  float res[2][4][4];
  float s1[2][4], s2[2][4];
#pragma unroll
  for (int fi = 0; fi < 2; ++fi)
#pragma unroll
    for (int r = 0; r < 4; ++r) { s1[fi][r] = 0.f; s2[fi][r] = 0.f; }

#pragma unroll
  for (int fj = 0; fj < 4; ++fj) {
    int col = w * 64 + fj * 16 + lr;
    float bcol = p.bf_[col];
#pragma unroll
    for (int fi = 0; fi < 2; ++fi)
#pragma unroll
      for (int r = 0; r < 4; ++r) {
        int rowl = fi * 16 + lk * 4 + r;
        int sr = sm.pl.srcs[rowl];
        float qv = (sr >= 0) ? p.query[(size_t)sr * D + col] : 0.f;
        float v = acc[fi][fj][r] + bcol + qv;
        res[fi][fj][r] = v;
        s1[fi][r] += v;
        s2[fi][r] += v * v;
      }
  }

#pragma unroll
  for (int o2 = 1; o2 <= 8; o2 <<= 1) {
#pragma unroll
    for (int fi = 0; fi < 2; ++fi)
#pragma unroll
      for (int r = 0; r < 4; ++r) {
        s1[fi][r] += __shfl_xor(s1[fi][r], o2, 64);
        s2[fi][r] += __shfl_xor(s2[fi][r], o2, 64);
      }
  }
  if (lr == 0) {
#pragma unroll
    for (int fi = 0; fi < 2; ++fi)
#pragma unroll
      for (int r = 0; r < 4; ++r) {
        int rowl = fi * 16 + lk * 4 + r;
        sm.pl.psum[w][rowl] = s1[fi][r];
        sm.pl.psum2[w][rowl] = s2[fi][r];
      }
  }
  __syncthreads();
  if (t < 32) {
    float tot = sm.pl.psum[0][t] + sm.pl.psum[1][t] + sm.pl.psum[2][t] + sm.pl.psum[3][t];
    float tot2 = sm.pl.psum2[0][t] + sm.pl.psum2[1][t] + sm.pl.psum2[2][t] + sm.pl.psum2[3][t];
    float mu = tot * (1.f / D);
    float var = tot2 * (1.f / D) - mu * mu;
    sm.pl.mu_s[t] = mu;
    sm.pl.is_s[t] = rsqrtf(var + 1e-5f);
  }
  __syncthreads();

#pragma unroll
  for (int fj = 0; fj < 4; ++fj) {
    int col = w * 64 + fj * 16 + lr;
    float gc = p.gamma[col], bc = p.beta[col];
#pragma unroll
    for (int fi = 0; fi < 2; ++fi)
#pragma unroll
      for (int r = 0; r < 4; ++r) {
        int rowl = fi * 16 + lk * 4 + r;
        int sr = sm.pl.srcs[rowl];
        if (sr >= 0)
          p.out[(size_t)sr * D + col] =
              (res[fi][fj][r] - sm.pl.mu_s[rowl]) * sm.pl.is_s[rowl] * gc + bc;
      }
  }
}

// ---------------------------------------------------------------------------
// Mega kernel. __launch_bounds__(BLK, 2): min 2 blocks/CU (VGPR capped at
// 128) so a <=512-block cooperative grid is guaranteed co-resident.
// ---------------------------------------------------------------------------
__global__ __launch_bounds__(BLK, 2) void mega(P p) {
  __shared__ SMem sm;
  cg::grid_group grid = cg::this_grid();

  for (int ph = p.phase_lo; ph <= p.phase_hi; ++ph) {
    int njobs;
    int ntq = 0, ntk = 0;
    if (ph == 0) njobs = 19 + 28 * 16;
    else {
      ntq = p.ntl[0]; ntk = p.ntl[1];
      njobs = (ph == 1) ? (ntq * 4 + ntk * 4)
            : (ph == 2) ? (ntq * H * SPLITK)
                        : (ntq * 4);
    }
    for (int job = blockIdx.x; job < njobs; job += gridDim.x) {
      __syncthreads();
      if (ph == 0) {
        ph_prep(p, sm, job);
      } else if (ph == 1) {
        int n0 = ntq * 4, n1 = n0 + ntk * 2;
        int y, ti, sub;
        if (job < n0)      { y = 0; ti = job >> 2; sub = job & 3; }
        else if (job < n1) { int j = job - n0; y = 1; ti = j >> 1; sub = j & 1; }
        else               { int j = job - n1; y = 2; ti = j >> 1; sub = j & 1; }
        ph_gemm(p, y, ti, sub);
      } else if (ph == 2) {
        ph_attn(p, sm, job >> 4, (job >> 2) & 3, job & 3);
      } else {
        ph_proj(p, sm, job >> 2, job & 3);
      }
    }
    if (ph < p.phase_hi) {
      __threadfence();
      grid.sync();
    }
  }
}

// ---------------------------------------------------------------------------
extern "C" void kernel_launch(void* const* d_in, const int* in_sizes, int n_in,
                              void* d_out, int out_size, void* d_ws, size_t ws_size,
                              hipStream_t stream) {
  const int N = in_sizes[0] / D;
  const int M = in_sizes[2] / D;
  const int TQCAP = (M + 127) / 128 + NLBL;
  const int TKCAP = (N + 63) / 64 + NLBL;

  P p;
  p.key   = (const float*)d_in[0];
  p.value = (const float*)d_in[1];
  p.query = (const float*)d_in[2];
  p.lbl1  = (const int*)d_in[3];
  p.lbl2  = (const int*)d_in[4];
  p.Wq = (const float*)d_in[5];
  p.bq = (const float*)d_in[6];
  p.Wk = (const float*)d_in[7];
  p.bk = (const float*)d_in[8];
  p.Wv = (const float*)d_in[9];
  p.bv = (const float*)d_in[10];
  p.Wf = (const float*)d_in[11];
  p.bf_ = (const float*)d_in[12];
  p.gamma = (const float*)d_in[13];
  p.beta  = (const float*)d_in[14];
  p.out = (float*)d_out;
  p.N = N; p.M = M;

  const int MP = M + NLBL * 128;
  const int NP = N + NLBL * 64;

  p.cnt = (int*)d_ws;
  p.off = p.cnt + 32;
  p.pqo = p.off + 32;
  p.pko = p.pqo + 16;
  p.ntl = p.pko + 16;
  p.tq  = p.ntl + 16;
  p.tk  = p.tq + 2 * TQCAP;
  p.korder = p.tk + 2 * TKCAP;
  p.qorder = p.korder + N;
  size_t ihdr = (((size_t)(112 + 2 * TQCAP + 2 * TKCAP + N + M)) * 4 + 255) & ~(size_t)255;

  p.Wqt = (__bf16*)((char*)d_ws + ihdr);
  p.Wkt = p.Wqt + (size_t)9 * 65536;
  p.Wvt = p.Wkt + (size_t)9 * 65536;
  p.Wft = p.Wvt + (size_t)9 * 65536;
  p.qbuf = p.Wft + 65536;
  p.kbuf = p.qbuf + (size_t)MP * D;
  p.vbuf = p.kbuf + (size_t)NP * D;
  p.pctx = p.vbuf + (size_t)NP * D;                         // TQCAP*H*SPLITK*8192 bf16
  p.pstats = (float*)(p.pctx + (size_t)TQCAP * H * SPLITK * 8192);  // *128 f32

  // Verified co-residency: occupancy query (pure host-side, deterministic,
  // capture-safe) bounds the cooperative grid.
  int occ = 0;
  hipError_t qe = hipOccupancyMaxActiveBlocksPerMultiprocessor(
      &occ, reinterpret_cast<const void*>(&mega), BLK, 0);

  bool coop_ok = false;
  if (qe == hipSuccess && occ >= 1) {
    int grid = occ * 256;            // 256 CUs on MI355X
    if (grid > GRID) grid = GRID;
    p.phase_lo = 0; p.phase_hi = 3;
    void* kargs[] = {&p};
    hipError_t e = hipLaunchCooperativeKernel(
        reinterpret_cast<const void*>(&mega), dim3(grid), dim3(BLK), kargs, 0, stream);
    if (e == hipSuccess) coop_ok = true;
    else (void)hipGetLastError();    // clear error state
  } else {
    (void)hipGetLastError();
  }

  if (!coop_ok) {
    // Fallback: one phase per dispatch (identical math, no grid.sync).
    for (int ph = 0; ph < 4; ++ph) {
      P q = p;
      q.phase_lo = ph; q.phase_hi = ph;
      mega<<<dim3(GRID), dim3(BLK), 0, stream>>>(q);
    }
  }
}

// Round 11
// 87.342 us; speedup vs baseline: 3.5628x; 3.5628x over previous
//
#include <hip/hip_runtime.h>
#include <hip/hip_bf16.h>

#define D 256
#define H 4
#define DPH 64
#define NLBL 9
#define SPLITK 2

typedef __attribute__((ext_vector_type(8))) __bf16 bf16x8;
typedef __attribute__((ext_vector_type(8))) unsigned short u16x8;
typedef __attribute__((ext_vector_type(4))) float f32x4;

__device__ __forceinline__ int sw_idx(int row, int col) {
  // ushort-unit index into a [R][64] bf16 LDS tile, XOR-swizzled.
  return row * 64 + (col ^ ((row & 7) << 3));
}

__device__ __forceinline__ unsigned int pk2(float a, float b) {
  unsigned int lo = (unsigned int)__builtin_bit_cast(unsigned short, (__bf16)a);
  unsigned int hi = (unsigned int)__builtin_bit_cast(unsigned short, (__bf16)b);
  return lo | (hi << 16);
}

__device__ __forceinline__ float b2f(unsigned short u) {
  return __builtin_bit_cast(float, (unsigned int)u << 16);
}

__device__ __forceinline__ bf16x8 cvt8(float4 u0, float4 u1) {
  bf16x8 r;
  r[0] = (__bf16)u0.x; r[1] = (__bf16)u0.y; r[2] = (__bf16)u0.z; r[3] = (__bf16)u0.w;
  r[4] = (__bf16)u1.x; r[5] = (__bf16)u1.y; r[6] = (__bf16)u1.z; r[7] = (__bf16)u1.w;
  return r;
}

// ---------------------------------------------------------------------------
// Fused prep: jobs 0..17 = stable scatter (each block computes its own
// histogram+prefix, no cross-block dep); job 18 = offsets/tile tables;
// jobs 19.. = weight transpose+cast (28 matrices x 16 subtiles).
// ---------------------------------------------------------------------------
__global__ __launch_bounds__(1024) void prep_kernel(
    const int* __restrict__ lbl1, int n1, const int* __restrict__ lbl2, int n2,
    const float* __restrict__ Wq, const float* __restrict__ Wk,
    const float* __restrict__ Wv, const float* __restrict__ Wf,
    __bf16* __restrict__ Wqt, __bf16* __restrict__ Wkt,
    __bf16* __restrict__ Wvt, __bf16* __restrict__ Wft,
    int* __restrict__ cnt, int* __restrict__ off,
    int* __restrict__ pqo, int* __restrict__ pko,
    int* __restrict__ tq, int* __restrict__ tk, int* __restrict__ ntl,
    int* __restrict__ korder, int* __restrict__ qorder) {
  const int job = blockIdx.x;
  const int t = threadIdx.x, lane = t & 63, wave = t >> 6;

  __shared__ int bins[2 * NLBL];
  __shared__ int wtot[16];
  __shared__ float tlds[64][65];

  if (job < 18) {
    // ---- stable scatter for (label l, side a)
    const int l = job % NLBL, a = job / NLBL;
    const int n = a ? n2 : n1;
    const int* lbl = a ? lbl2 : lbl1;
    int* order = a ? qorder : korder;

    if (t < NLBL) bins[t] = 0;
    __syncthreads();
    for (int chunk = 0; chunk < n; chunk += 1024) {
      int i = chunk + t;
      int lb = (i < n) ? lbl[i] : -1;
#pragma unroll
      for (int lab = 0; lab < NLBL; ++lab) {
        unsigned long long bal = __ballot(lb == lab);
        if (lane == 0 && bal) atomicAdd(&bins[lab], __popcll(bal));
      }
    }
    __syncthreads();
    int base = 0;
#pragma unroll
    for (int i = 0; i < NLBL; ++i) base += (i < l) ? bins[i] : 0;

    int pos = 0;
    for (int chunk = 0; chunk < n; chunk += 1024) {
      int i = chunk + t;
      bool flag = (i < n) && (lbl[i] == l);
      unsigned long long bal = __ballot(flag);
      int wprefix = __popcll(bal & ((1ull << lane) - 1ull));
      if (lane == 0) wtot[wave] = __popcll(bal);
      __syncthreads();
      int prew = 0, tot = 0;
#pragma unroll
      for (int w = 0; w < 16; ++w) {
        prew += (w < wave) ? wtot[w] : 0;
        tot += wtot[w];
      }
      if (flag) order[base + pos + prew + wprefix] = i;
      pos += tot;
      __syncthreads();
    }
    return;
  }

  if (job == 18) {
    // ---- histogram both sides + build all tables
    if (t < 2 * NLBL) bins[t] = 0;
    __syncthreads();
    for (int a = 0; a < 2; ++a) {
      const int n = a ? n2 : n1;
      const int* lbl = a ? lbl2 : lbl1;
      for (int chunk = 0; chunk < n; chunk += 1024) {
        int i = chunk + t;
        int lb = (i < n) ? lbl[i] : -1;
#pragma unroll
        for (int lab = 0; lab < NLBL; ++lab) {
          unsigned long long bal = __ballot(lb == lab);
          if (lane == 0 && bal) atomicAdd(&bins[a * NLBL + lab], __popcll(bal));
        }
      }
    }
    __syncthreads();
    if (t < 2 * NLBL) cnt[t] = bins[t];
    if (t == 0) {
      int a0 = 0, a1 = 0, p0 = 0, p1 = 0, t0 = 0, t1 = 0;
      for (int l = 0; l < NLBL; ++l) {
        off[l] = a0;      a0 += bins[l];
        off[10 + l] = a1; a1 += bins[NLBL + l];
        pko[l] = p0; pqo[l] = p1;
        int tkl = (bins[l] + 63) >> 6;
        int tql = (bins[NLBL + l] + 127) >> 7;
        for (int i = 0; i < tkl; ++i) { tk[2 * t0] = l; tk[2 * t0 + 1] = p0 + (i << 6); ++t0; }
        for (int i = 0; i < tql; ++i) { tq[2 * t1] = l; tq[2 * t1 + 1] = p1 + (i << 7); ++t1; }
        p0 += tkl << 6; p1 += tql << 7;
      }
      off[9] = a0; off[19] = a1; pko[9] = p0; pqo[9] = p1;
      ntl[0] = t1; ntl[1] = t0;
    }
    return;
  }

  // ---- weight transpose+cast: Wt[n][k] = bf16(W[k][n])
  {
    int j = job - 19;
    int m = j >> 4, sub = j & 15;
    const float* src; __bf16* dst;
    if (m < 9)       { src = Wq + (size_t)m * 65536;        dst = Wqt + (size_t)m * 65536; }
    else if (m < 18) { src = Wk + (size_t)(m - 9) * 65536;  dst = Wkt + (size_t)(m - 9) * 65536; }
    else if (m < 27) { src = Wv + (size_t)(m - 18) * 65536; dst = Wvt + (size_t)(m - 18) * 65536; }
    else             { src = Wf;                            dst = Wft; }
    int k0 = (sub >> 2) << 6, n0 = (sub & 3) << 6;
    int rr = t >> 6, c = t & 63;
#pragma unroll
    for (int i = 0; i < 4; ++i) {
      int r = i * 16 + rr;
      tlds[r][c] = src[(size_t)(k0 + r) * D + n0 + c];
    }
    __syncthreads();
#pragma unroll
    for (int i = 0; i < 4; ++i) {
      int r = i * 16 + rr;
      dst[(size_t)(n0 + r) * D + k0 + c] = (__bf16)tlds[c][r];
    }
  }
}

// ---------------------------------------------------------------------------
// Label-routed input projections via MFMA bf16 -> bf16 sorted-padded buffers.
// 32-row x 256-col tiles. Query branch pre-scales by 0.25*log2(e).
// y=0: query (128-tiles /4), y=1: key, y=2: value (64-tiles /2).
// ---------------------------------------------------------------------------
__global__ __launch_bounds__(256) void gemm_in_kernel(
    const float* __restrict__ query, const float* __restrict__ key,
    const float* __restrict__ value,
    const __bf16* __restrict__ Wqt, const __bf16* __restrict__ Wkt,
    const __bf16* __restrict__ Wvt,
    const float* __restrict__ bq, const float* __restrict__ bk,
    const float* __restrict__ bv,
    const int* __restrict__ qorder, const int* __restrict__ korder,
    const int* __restrict__ off, const int* __restrict__ cnt,
    const int* __restrict__ pqo, const int* __restrict__ pko,
    const int* __restrict__ tq, const int* __restrict__ tk,
    const int* __restrict__ ntl,
    __bf16* __restrict__ qbuf, __bf16* __restrict__ kbuf, __bf16* __restrict__ vbuf) {
  const int y = blockIdx.y;
  const int nt = (y == 0) ? ntl[0] : ntl[1];
  const int ti = (y == 0) ? ((int)blockIdx.x >> 2) : ((int)blockIdx.x >> 1);
  const int sub = (y == 0) ? ((int)blockIdx.x & 3) : ((int)blockIdx.x & 1);
  if (ti >= nt) return;
  const int* tt = (y == 0) ? tq : tk;
  const float* x = (y == 0) ? query : (y == 1 ? key : value);
  const __bf16* W = (y == 0) ? Wqt : (y == 1 ? Wkt : Wvt);
  const float* bias = (y == 0) ? bq : (y == 1 ? bk : bv);
  const int* order = (y == 0) ? qorder : korder;
  const int* po = (y == 0) ? pqo : pko;
  __bf16* outp = (y == 0) ? qbuf : (y == 1 ? kbuf : vbuf);
  const float sc = (y == 0) ? 0.36067376f : 1.0f;   // 0.25 * log2(e)

  const int l = tt[2 * ti], prow0 = tt[2 * ti + 1] + sub * 32;
  const int cl = (y == 0) ? cnt[NLBL + l] : cnt[l];
  const int ooff = (y == 0) ? off[10 + l] : off[l];
  const int base = prow0 - po[l];

  const int t = threadIdx.x, w = t >> 6, lane = t & 63;
  const int lr = lane & 15, lk = lane >> 4;

  int src[2];
#pragma unroll
  for (int fi = 0; fi < 2; ++fi) {
    int ridx = base + fi * 16 + lr;
    src[fi] = (ridx < cl) ? order[ooff + ridx] : -1;
  }

  bf16x8 az;
#pragma unroll
  for (int j = 0; j < 8; ++j) az[j] = (__bf16)0.f;

  f32x4 acc[2][4];
#pragma unroll
  for (int i = 0; i < 2; ++i)
#pragma unroll
    for (int j = 0; j < 4; ++j) acc[i][j] = (f32x4){0.f, 0.f, 0.f, 0.f};

  for (int kb = 0; kb < 8; ++kb) {
    const int kbase = kb * 32 + lk * 8;
    bf16x8 a[2], b[4];
#pragma unroll
    for (int fi = 0; fi < 2; ++fi) {
      if (src[fi] >= 0) {
        const float* ap = x + (size_t)src[fi] * D + kbase;
        float4 u0 = *(const float4*)ap;
        float4 u1 = *(const float4*)(ap + 4);
        a[fi] = cvt8(u0, u1);
      } else {
        a[fi] = az;
      }
    }
#pragma unroll
    for (int fj = 0; fj < 4; ++fj) {
      int col = w * 64 + fj * 16 + lr;
      b[fj] = *(const bf16x8*)(W + (size_t)l * 65536 + (size_t)col * D + kbase);
    }
#pragma unroll
    for (int fi = 0; fi < 2; ++fi)
#pragma unroll
      for (int fj = 0; fj < 4; ++fj)
        acc[fi][fj] = __builtin_amdgcn_mfma_f32_16x16x32_bf16(a[fi], b[fj], acc[fi][fj], 0, 0, 0);
  }

#pragma unroll
  for (int fj = 0; fj < 4; ++fj) {
    int col = w * 64 + fj * 16 + lr;
    float bv_ = bias[l * D + col];
#pragma unroll
    for (int fi = 0; fi < 2; ++fi)
#pragma unroll
      for (int r = 0; r < 4; ++r) {
        int row = prow0 + fi * 16 + lk * 4 + r;
        outp[(size_t)row * D + col] = (__bf16)((acc[fi][fj][r] + bv_) * sc);
      }
  }
}

// ---------------------------------------------------------------------------
// Split-K MFMA flash attention, 128-query tiles, no-max softmax, register
// prefetch of next K/V tile (HBM latency hidden under MFMA+softmax).
// Partials stored bf16. grid=(TQ128CAP, H, SPLITK).
// ---------------------------------------------------------------------------
__global__ __launch_bounds__(256) void attn_mfma(
    const __bf16* __restrict__ qbuf, const __bf16* __restrict__ kbuf,
    const __bf16* __restrict__ vbuf, const int* __restrict__ cnt,
    const int* __restrict__ tq, const int* __restrict__ ntl,
    const int* __restrict__ pko,
    __bf16* __restrict__ pctx, float* __restrict__ pstats) {
  const int tqi = blockIdx.x;
  if (tqi >= ntl[0]) return;
  const int l = tq[2 * tqi], prow0 = tq[2 * tqi + 1];
  const int h = blockIdx.y, s = blockIdx.z;
  const int nk = cnt[l];
  const int ntiles = (nk + 63) >> 6;
  const int ntsz = (ntiles + SPLITK - 1) / SPLITK;
  const int tt0 = s * ntsz;
  const int tt1 = min(ntiles, tt0 + ntsz);
  if (tt0 >= tt1) return;

  const int t = threadIdx.x;
  const int w = t >> 6, lane = t & 63;
  const int lr = lane & 15, lk = lane >> 4;

  __shared__ __align__(16) unsigned short ks[4096];    // K tile [key][d]
  __shared__ __align__(16) unsigned short vtl[4096];   // V tile [d][key]
  __shared__ __align__(16) unsigned short plds[8192];  // P [wave][32q][64k]

  const int qbase = prow0 + w * 32;
  bf16x8 b_q[2][2];
#pragma unroll
  for (int qf = 0; qf < 2; ++qf)
#pragma unroll
    for (int kb = 0; kb < 2; ++kb)
      b_q[qf][kb] = *(const bf16x8*)(qbuf + (size_t)(qbase + qf * 16 + lr) * D +
                                     h * DPH + kb * 32 + lk * 8);

  f32x4 acc_o[2][4];
#pragma unroll
  for (int qf = 0; qf < 2; ++qf)
#pragma unroll
    for (int i = 0; i < 4; ++i) acc_o[qf][i] = (f32x4){0.f, 0.f, 0.f, 0.f};
  float lrun[2] = {0.f, 0.f};
  const int kb0 = pko[l];

  // per-thread staging addresses (tile-invariant parts)
  const int krow = t >> 2, kc0 = (t & 3) * 16;
  const __bf16* kptr = kbuf + (size_t)(kb0 + krow) * D + h * DPH + kc0;
  const int vkey2 = (t & 31) * 2, vd0 = (t >> 5) * 8;
  const __bf16* vptr = vbuf + (size_t)(kb0 + vkey2) * D + h * DPH + vd0;

  uint4 kreg0, kreg1;
  u16x8 vreg0, vreg1;
  auto LOADT = [&](int tt) {
    const __bf16* kp = kptr + ((size_t)tt << 6) * D;
    kreg0 = *(const uint4*)kp;
    kreg1 = *(const uint4*)(kp + 8);
    const __bf16* vp = vptr + ((size_t)tt << 6) * D;
    vreg0 = *(const u16x8*)vp;
    vreg1 = *(const u16x8*)(vp + D);
  };

  LOADT(tt0);
  for (int tt = tt0; tt < tt1; ++tt) {
    const int n0 = tt << 6;
    __syncthreads();
    // ---- write staged regs -> swizzled LDS
    *(uint4*)&ks[sw_idx(krow, kc0)] = kreg0;
    *(uint4*)&ks[sw_idx(krow, kc0 + 8)] = kreg1;
#pragma unroll
    for (int j = 0; j < 8; ++j) {
      unsigned int u = (unsigned int)vreg0[j] | ((unsigned int)vreg1[j] << 16);
      *(unsigned int*)&vtl[sw_idx(vd0 + j, vkey2)] = u;
    }
    __syncthreads();
    // ---- prefetch next tile while computing this one
    if (tt + 1 < tt1) LOADT(tt + 1);

    // ---- S^T = K x Q^T : C[key][q], key = fi*16+lk*4+r, q = qf*16+lr
    f32x4 s_acc[2][4];
    const f32x4 zz = {0.f, 0.f, 0.f, 0.f};
#pragma unroll
    for (int fi = 0; fi < 4; ++fi) {
      bf16x8 a0 = *(const bf16x8*)&ks[sw_idx(fi * 16 + lr, lk * 8)];
#pragma unroll
      for (int qf = 0; qf < 2; ++qf)
        s_acc[qf][fi] = __builtin_amdgcn_mfma_f32_16x16x32_bf16(a0, b_q[qf][0], zz, 0, 0, 0);
    }
#pragma unroll
    for (int fi = 0; fi < 4; ++fi) {
      bf16x8 a1 = *(const bf16x8*)&ks[sw_idx(fi * 16 + lr, 32 + lk * 8)];
#pragma unroll
      for (int qf = 0; qf < 2; ++qf)
        s_acc[qf][fi] = __builtin_amdgcn_mfma_f32_16x16x32_bf16(a1, b_q[qf][1], s_acc[qf][fi], 0, 0, 0);
    }

    // ---- softmax weights, no max subtraction (bounded logits, fp32 exp2)
    float p[2][16];
#pragma unroll
    for (int qf = 0; qf < 2; ++qf) {
      float ts = 0.f;
#pragma unroll
      for (int fi = 0; fi < 4; ++fi)
#pragma unroll
        for (int r = 0; r < 4; ++r) {
          int key = n0 + fi * 16 + lk * 4 + r;
          float pv = (key < nk) ? exp2f(s_acc[qf][fi][r]) : 0.f;
          p[qf][fi * 4 + r] = pv;
          ts += pv;
        }
      ts += __shfl_xor(ts, 16, 64);
      ts += __shfl_xor(ts, 32, 64);
      lrun[qf] += ts;
    }

    // ---- P -> per-wave LDS (bf16, swizzled)
#pragma unroll
    for (int qf = 0; qf < 2; ++qf)
#pragma unroll
      for (int fi = 0; fi < 4; ++fi) {
        unsigned int w0 = pk2(p[qf][fi * 4 + 0], p[qf][fi * 4 + 1]);
        unsigned int w1 = pk2(p[qf][fi * 4 + 2], p[qf][fi * 4 + 3]);
        int idx = w * 2048 + sw_idx(qf * 16 + lr, fi * 16 + lk * 4);
        *(uint2*)&plds[idx] = make_uint2(w0, w1);
      }

    // ---- O^T += V^T x P : C[d][q], d = fi*16+lk*4+r
#pragma unroll
    for (int kb = 0; kb < 2; ++kb) {
      bf16x8 bp[2];
#pragma unroll
      for (int qf = 0; qf < 2; ++qf)
        bp[qf] = *(const bf16x8*)&plds[w * 2048 + sw_idx(qf * 16 + lr, kb * 32 + lk * 8)];
#pragma unroll
      for (int fi = 0; fi < 4; ++fi) {
        bf16x8 av = *(const bf16x8*)&vtl[sw_idx(fi * 16 + lr, kb * 32 + lk * 8)];
#pragma unroll
        for (int qf = 0; qf < 2; ++qf)
          acc_o[qf][fi] = __builtin_amdgcn_mfma_f32_16x16x32_bf16(av, bp[qf], acc_o[qf][fi], 0, 0, 0);
      }
    }
  }

  // ---- write partials (bf16)
  const size_t pbase = ((size_t)tqi * H + h) * SPLITK + s;
  __bf16* pc = pctx + pbase * 8192;
#pragma unroll
  for (int qf = 0; qf < 2; ++qf) {
    int qloc = w * 32 + qf * 16 + lr;
#pragma unroll
    for (int fi = 0; fi < 4; ++fi) {
      uint2 u;
      u.x = pk2(acc_o[qf][fi][0], acc_o[qf][fi][1]);
      u.y = pk2(acc_o[qf][fi][2], acc_o[qf][fi][3]);
      *(uint2*)(pc + qloc * 64 + fi * 16 + lk * 4) = u;
    }
    if (lk == 0) pstats[pbase * 128 + qloc] = lrun[qf];
  }
}

// ---------------------------------------------------------------------------
// Fused: merge bf16 split-K partials -> normalized bf16 ctx in LDS -> @Wf
// + bias + residual -> LayerNorm -> scatter to out. grid=(TQ128CAP, 4).
// ---------------------------------------------------------------------------
__global__ __launch_bounds__(256) void proj_ln_kernel(
    const __bf16* __restrict__ pctx, const float* __restrict__ pstats,
    const __bf16* __restrict__ Wft, const float* __restrict__ bf_,
    const float* __restrict__ query,
    const int* __restrict__ qorder, const int* __restrict__ off,
    const int* __restrict__ cnt, const int* __restrict__ pqo,
    const int* __restrict__ tq, const int* __restrict__ ntl,
    const float* __restrict__ gamma, const float* __restrict__ beta,
    float* __restrict__ out) {
  const int tqi = blockIdx.x;
  if (tqi >= ntl[0]) return;
  const int l = tq[2 * tqi];
  const int qq = blockIdx.y;
  const int prow0 = tq[2 * tqi + 1] + qq * 32;
  const int qloc0 = qq * 32;
  const int cl = cnt[NLBL + l];
  const int ooff = off[10 + l];
  const int base = prow0 - pqo[l];
  const int nk = cnt[l];
  const int ntiles = (nk + 63) >> 6;
  const int ntsz = (ntiles + SPLITK - 1) / SPLITK;
  const int nsp = ntiles ? (ntiles + ntsz - 1) / ntsz : 0;

  const int t = threadIdx.x, w = t >> 6, lane = t & 63;
  const int lr = lane & 15, lk = lane >> 4;

  __shared__ int srcs[32];
  __shared__ float linv[32][4];
  __shared__ __align__(16) unsigned short ct[32 * 256];  // merged ctx, swizzled
  __shared__ float psum[4][32], psum2[4][32];
  __shared__ float mu_s[32], is_s[32];

  if (t < 32) {
    int ridx = base + t;
    srcs[t] = (ridx < cl) ? qorder[ooff + ridx] : -1;
  }
  if (t < 128) {
    int row = t >> 2, h = t & 3;
    float L = 0.f;
    for (int s = 0; s < nsp; ++s)
      L += pstats[(((size_t)tqi * H + h) * SPLITK + s) * 128 + qloc0 + row];
    linv[row][h] = (L > 0.f) ? (1.f / L) : 0.f;
  }
  __syncthreads();

  // ---- merge bf16 pctx across splits -> normalized bf16 in ct
  {
    int row = t >> 3, dseg = (t & 7) * 32;
    int h = dseg >> 6, d0 = dseg & 63;
    const __bf16* pb = pctx + (((size_t)tqi * H + h) * SPLITK) * 8192 +
                       (size_t)(qloc0 + row) * 64 + d0;
    float v[32];
#pragma unroll
    for (int j = 0; j < 32; ++j) v[j] = 0.f;
    for (int s = 0; s < nsp; ++s) {
      const __bf16* ps = pb + (size_t)s * 8192;
#pragma unroll
      for (int j4 = 0; j4 < 4; ++j4) {
        u16x8 u = *(const u16x8*)(ps + j4 * 8);
#pragma unroll
        for (int e = 0; e < 8; ++e) v[j4 * 8 + e] += b2f(u[e]);
      }
    }
    float iv = linv[row][h];
    int xr = (row & 7) << 3;
#pragma unroll
    for (int j = 0; j < 32; j += 2)
      *(unsigned int*)&ct[row * 256 + ((dseg + j) ^ xr)] = pk2(v[j] * iv, v[j + 1] * iv);
  }
  __syncthreads();

  // ---- GEMM: res32 = ct @ Wf
  f32x4 acc[2][4];
#pragma unroll
  for (int i = 0; i < 2; ++i)
#pragma unroll
    for (int j = 0; j < 4; ++j) acc[i][j] = (f32x4){0.f, 0.f, 0.f, 0.f};

  for (int kb = 0; kb < 8; ++kb) {
    const int kbase = kb * 32 + lk * 8;
    bf16x8 a[2], b[4];
#pragma unroll
    for (int fi = 0; fi < 2; ++fi) {
      int row = fi * 16 + lr;
      a[fi] = *(const bf16x8*)&ct[row * 256 + (kbase ^ ((row & 7) << 3))];
    }
#pragma unroll
    for (int fj = 0; fj < 4; ++fj) {
      int col = w * 64 + fj * 16 + lr;
      b[fj] = *(const bf16x8*)(Wft + (size_t)col * D + kbase);
    }
#pragma unroll
    for (int fi = 0; fi < 2; ++fi)
#pragma unroll
      for (int fj = 0; fj < 4; ++fj)
        acc[fi][fj] = __builtin_amdgcn_mfma_f32_16x16x32_bf16(a[fi], b[fj], acc[fi][fj], 0, 0, 0);
  }

  float res[2][4][4];
  float s1[2][4], s2[2][4];
#pragma unroll
  for (int fi = 0; fi < 2; ++fi)
#pragma unroll
    for (int r = 0; r < 4; ++r) { s1[fi][r] = 0.f; s2[fi][r] = 0.f; }

#pragma unroll
  for (int fj = 0; fj < 4; ++fj) {
    int col = w * 64 + fj * 16 + lr;
    float bcol = bf_[col];
#pragma unroll
    for (int fi = 0; fi < 2; ++fi)
#pragma unroll
      for (int r = 0; r < 4; ++r) {
        int rowl = fi * 16 + lk * 4 + r;
        int sr = srcs[rowl];
        float qv = (sr >= 0) ? query[(size_t)sr * D + col] : 0.f;
        float v = acc[fi][fj][r] + bcol + qv;
        res[fi][fj][r] = v;
        s1[fi][r] += v;
        s2[fi][r] += v * v;
      }
  }

#pragma unroll
  for (int o2 = 1; o2 <= 8; o2 <<= 1) {
#pragma unroll
    for (int fi = 0; fi < 2; ++fi)
#pragma unroll
      for (int r = 0; r < 4; ++r) {
        s1[fi][r] += __shfl_xor(s1[fi][r], o2, 64);
        s2[fi][r] += __shfl_xor(s2[fi][r], o2, 64);
      }
  }
  if (lr == 0) {
#pragma unroll
    for (int fi = 0; fi < 2; ++fi)
#pragma unroll
      for (int r = 0; r < 4; ++r) {
        int rowl = fi * 16 + lk * 4 + r;
        psum[w][rowl] = s1[fi][r];
        psum2[w][rowl] = s2[fi][r];
      }
  }
  __syncthreads();
  if (t < 32) {
    float tot = psum[0][t] + psum[1][t] + psum[2][t] + psum[3][t];
    float tot2 = psum2[0][t] + psum2[1][t] + psum2[2][t] + psum2[3][t];
    float mu = tot * (1.f / D);
    float var = tot2 * (1.f / D) - mu * mu;
    mu_s[t] = mu;
    is_s[t] = rsqrtf(var + 1e-5f);
  }
  __syncthreads();

#pragma unroll
  for (int fj = 0; fj < 4; ++fj) {
    int col = w * 64 + fj * 16 + lr;
    float gc = gamma[col], bc = beta[col];
#pragma unroll
    for (int fi = 0; fi < 2; ++fi)
#pragma unroll
      for (int r = 0; r < 4; ++r) {
        int rowl = fi * 16 + lk * 4 + r;
        int sr = srcs[rowl];
        if (sr >= 0)
          out[(size_t)sr * D + col] =
              (res[fi][fj][r] - mu_s[rowl]) * is_s[rowl] * gc + bc;
      }
  }
}

// ---------------------------------------------------------------------------
extern "C" void kernel_launch(void* const* d_in, const int* in_sizes, int n_in,
                              void* d_out, int out_size, void* d_ws, size_t ws_size,
                              hipStream_t stream) {
  const float* key   = (const float*)d_in[0];
  const float* value = (const float*)d_in[1];
  const float* query = (const float*)d_in[2];
  const int*   lbl1  = (const int*)d_in[3];
  const int*   lbl2  = (const int*)d_in[4];
  const float* Wq = (const float*)d_in[5];
  const float* bq = (const float*)d_in[6];
  const float* Wk = (const float*)d_in[7];
  const float* bk = (const float*)d_in[8];
  const float* Wv = (const float*)d_in[9];
  const float* bv = (const float*)d_in[10];
  const float* Wf = (const float*)d_in[11];
  const float* bf_ = (const float*)d_in[12];
  const float* gamma = (const float*)d_in[13];
  const float* beta  = (const float*)d_in[14];
  float* out = (float*)d_out;

  const int N = in_sizes[0] / D;
  const int M = in_sizes[2] / D;
  const int MP = M + NLBL * 128;              // query padded rows (128-aligned)
  const int NP = N + NLBL * 64;               // key padded rows (64-aligned)
  const int TQCAP = (M + 127) / 128 + NLBL;   // 128-row query tiles
  const int TKCAP = (N + 63) / 64 + NLBL;     // 64-row key tiles

  int* cnt = (int*)d_ws;
  int* off = cnt + 32;
  int* pqo = off + 32;
  int* pko = pqo + 16;
  int* ntl = pko + 16;
  int* tq  = ntl + 16;
  int* tk  = tq + 2 * TQCAP;
  int* korder = tk + 2 * TKCAP;
  int* qorder = korder + N;
  size_t ihdr = (((size_t)(112 + 2 * TQCAP + 2 * TKCAP + N + M)) * 4 + 255) & ~(size_t)255;

  __bf16* Wqt = (__bf16*)((char*)d_ws + ihdr);
  __bf16* Wkt = Wqt + (size_t)9 * 65536;
  __bf16* Wvt = Wkt + (size_t)9 * 65536;
  __bf16* Wft = Wvt + (size_t)9 * 65536;
  __bf16* qbuf = Wft + 65536;
  __bf16* kbuf = qbuf + (size_t)MP * D;
  __bf16* vbuf = kbuf + (size_t)NP * D;
  __bf16* pctx = vbuf + (size_t)NP * D;                        // TQCAP*H*SPLITK*8192 bf16
  float* pstats = (float*)(pctx + (size_t)TQCAP * H * SPLITK * 8192);  // *128 f32

  prep_kernel<<<19 + 28 * 16, 1024, 0, stream>>>(
      lbl1, N, lbl2, M, Wq, Wk, Wv, Wf, Wqt, Wkt, Wvt, Wft,
      cnt, off, pqo, pko, tq, tk, ntl, korder, qorder);

  int gx = TQCAP * 4 > TKCAP * 2 ? TQCAP * 4 : TKCAP * 2;
  gemm_in_kernel<<<dim3(gx, 3), 256, 0, stream>>>(
      query, key, value, Wqt, Wkt, Wvt, bq, bk, bv,
      qorder, korder, off, cnt, pqo, pko, tq, tk, ntl, qbuf, kbuf, vbuf);

  attn_mfma<<<dim3(TQCAP, H, SPLITK), 256, 0, stream>>>(
      qbuf, kbuf, vbuf, cnt, tq, ntl, pko, pctx, pstats);

  proj_ln_kernel<<<dim3(TQCAP, 4), 256, 0, stream>>>(
      pctx, pstats, Wft, bf_, query, qorder, off, cnt, pqo, tq, ntl,
      gamma, beta, out);
}

// Round 13
// 85.743 us; speedup vs baseline: 3.6292x; 1.0186x over previous
//
#include <hip/hip_runtime.h>
#include <hip/hip_bf16.h>

#define D 256
#define H 4
#define DPH 64
#define NLBL 9
#define SPLITK 2

typedef __attribute__((ext_vector_type(8))) __bf16 bf16x8;
typedef __attribute__((ext_vector_type(8))) unsigned short u16x8;
typedef __attribute__((ext_vector_type(4))) float f32x4;

__device__ __forceinline__ int sw_idx(int row, int col) {
  // ushort-unit index into a [R][64] bf16 LDS tile, XOR-swizzled.
  return row * 64 + (col ^ ((row & 7) << 3));
}

__device__ __forceinline__ unsigned int pk2(float a, float b) {
  unsigned int lo = (unsigned int)__builtin_bit_cast(unsigned short, (__bf16)a);
  unsigned int hi = (unsigned int)__builtin_bit_cast(unsigned short, (__bf16)b);
  return lo | (hi << 16);
}

__device__ __forceinline__ float b2f(unsigned short u) {
  return __builtin_bit_cast(float, (unsigned int)u << 16);
}

__device__ __forceinline__ bf16x8 cvt8(float4 u0, float4 u1) {
  bf16x8 r;
  r[0] = (__bf16)u0.x; r[1] = (__bf16)u0.y; r[2] = (__bf16)u0.z; r[3] = (__bf16)u0.w;
  r[4] = (__bf16)u1.x; r[5] = (__bf16)u1.y; r[6] = (__bf16)u1.z; r[7] = (__bf16)u1.w;
  return r;
}

// ---------------------------------------------------------------------------
// Fused prep: jobs 0..17 = stable scatter (each block computes its own
// histogram+prefix, no cross-block dep); job 18 = offsets/tile tables;
// jobs 19.. = weight transpose+cast (28 matrices x 16 subtiles).
// ---------------------------------------------------------------------------
__global__ __launch_bounds__(1024) void prep_kernel(
    const int* __restrict__ lbl1, int n1, const int* __restrict__ lbl2, int n2,
    const float* __restrict__ Wq, const float* __restrict__ Wk,
    const float* __restrict__ Wv, const float* __restrict__ Wf,
    __bf16* __restrict__ Wqt, __bf16* __restrict__ Wkt,
    __bf16* __restrict__ Wvt, __bf16* __restrict__ Wft,
    int* __restrict__ cnt, int* __restrict__ off,
    int* __restrict__ pqo, int* __restrict__ pko,
    int* __restrict__ tq, int* __restrict__ tk, int* __restrict__ ntl,
    int* __restrict__ korder, int* __restrict__ qorder) {
  const int job = blockIdx.x;
  const int t = threadIdx.x, lane = t & 63, wave = t >> 6;

  __shared__ int bins[2 * NLBL];
  __shared__ int wtot[16];
  __shared__ float tlds[64][65];

  if (job < 18) {
    // ---- stable scatter for (label l, side a)
    const int l = job % NLBL, a = job / NLBL;
    const int n = a ? n2 : n1;
    const int* lbl = a ? lbl2 : lbl1;
    int* order = a ? qorder : korder;

    if (t < NLBL) bins[t] = 0;
    __syncthreads();
    for (int chunk = 0; chunk < n; chunk += 1024) {
      int i = chunk + t;
      int lb = (i < n) ? lbl[i] : -1;
#pragma unroll
      for (int lab = 0; lab < NLBL; ++lab) {
        unsigned long long bal = __ballot(lb == lab);
        if (lane == 0 && bal) atomicAdd(&bins[lab], __popcll(bal));
      }
    }
    __syncthreads();
    int base = 0;
#pragma unroll
    for (int i = 0; i < NLBL; ++i) base += (i < l) ? bins[i] : 0;

    int pos = 0;
    for (int chunk = 0; chunk < n; chunk += 1024) {
      int i = chunk + t;
      bool flag = (i < n) && (lbl[i] == l);
      unsigned long long bal = __ballot(flag);
      int wprefix = __popcll(bal & ((1ull << lane) - 1ull));
      if (lane == 0) wtot[wave] = __popcll(bal);
      __syncthreads();
      int prew = 0, tot = 0;
#pragma unroll
      for (int w = 0; w < 16; ++w) {
        prew += (w < wave) ? wtot[w] : 0;
        tot += wtot[w];
      }
      if (flag) order[base + pos + prew + wprefix] = i;
      pos += tot;
      __syncthreads();
    }
    return;
  }

  if (job == 18) {
    // ---- histogram both sides + build all tables
    if (t < 2 * NLBL) bins[t] = 0;
    __syncthreads();
    for (int a = 0; a < 2; ++a) {
      const int n = a ? n2 : n1;
      const int* lbl = a ? lbl2 : lbl1;
      for (int chunk = 0; chunk < n; chunk += 1024) {
        int i = chunk + t;
        int lb = (i < n) ? lbl[i] : -1;
#pragma unroll
        for (int lab = 0; lab < NLBL; ++lab) {
          unsigned long long bal = __ballot(lb == lab);
          if (lane == 0 && bal) atomicAdd(&bins[a * NLBL + lab], __popcll(bal));
        }
      }
    }
    __syncthreads();
    if (t < 2 * NLBL) cnt[t] = bins[t];
    if (t == 0) {
      int a0 = 0, a1 = 0, p0 = 0, p1 = 0, t0 = 0, t1 = 0;
      for (int l = 0; l < NLBL; ++l) {
        off[l] = a0;      a0 += bins[l];
        off[10 + l] = a1; a1 += bins[NLBL + l];
        pko[l] = p0; pqo[l] = p1;
        int tkl = (bins[l] + 63) >> 6;
        int tql = (bins[NLBL + l] + 127) >> 7;
        for (int i = 0; i < tkl; ++i) { tk[2 * t0] = l; tk[2 * t0 + 1] = p0 + (i << 6); ++t0; }
        for (int i = 0; i < tql; ++i) { tq[2 * t1] = l; tq[2 * t1 + 1] = p1 + (i << 7); ++t1; }
        p0 += tkl << 6; p1 += tql << 7;
      }
      off[9] = a0; off[19] = a1; pko[9] = p0; pqo[9] = p1;
      ntl[0] = t1; ntl[1] = t0;
    }
    return;
  }

  // ---- weight transpose+cast: Wt[n][k] = bf16(W[k][n])
  {
    int j = job - 19;
    int m = j >> 4, sub = j & 15;
    const float* src; __bf16* dst;
    if (m < 9)       { src = Wq + (size_t)m * 65536;        dst = Wqt + (size_t)m * 65536; }
    else if (m < 18) { src = Wk + (size_t)(m - 9) * 65536;  dst = Wkt + (size_t)(m - 9) * 65536; }
    else if (m < 27) { src = Wv + (size_t)(m - 18) * 65536; dst = Wvt + (size_t)(m - 18) * 65536; }
    else             { src = Wf;                            dst = Wft; }
    int k0 = (sub >> 2) << 6, n0 = (sub & 3) << 6;
    int rr = t >> 6, c = t & 63;
#pragma unroll
    for (int i = 0; i < 4; ++i) {
      int r = i * 16 + rr;
      tlds[r][c] = src[(size_t)(k0 + r) * D + n0 + c];
    }
    __syncthreads();
#pragma unroll
    for (int i = 0; i < 4; ++i) {
      int r = i * 16 + rr;
      dst[(size_t)(n0 + r) * D + k0 + c] = (__bf16)tlds[c][r];
    }
  }
}

// ---------------------------------------------------------------------------
// Label-routed input projections via MFMA bf16 -> bf16 sorted-padded buffers.
// 32-row x 256-col tiles. Query branch pre-scales by 0.25*log2(e).
// y=0: query (128-tiles /4), y=1: key, y=2: value (64-tiles /2).
// ---------------------------------------------------------------------------
__global__ __launch_bounds__(256) void gemm_in_kernel(
    const float* __restrict__ query, const float* __restrict__ key,
    const float* __restrict__ value,
    const __bf16* __restrict__ Wqt, const __bf16* __restrict__ Wkt,
    const __bf16* __restrict__ Wvt,
    const float* __restrict__ bq, const float* __restrict__ bk,
    const float* __restrict__ bv,
    const int* __restrict__ qorder, const int* __restrict__ korder,
    const int* __restrict__ off, const int* __restrict__ cnt,
    const int* __restrict__ pqo, const int* __restrict__ pko,
    const int* __restrict__ tq, const int* __restrict__ tk,
    const int* __restrict__ ntl,
    __bf16* __restrict__ qbuf, __bf16* __restrict__ kbuf, __bf16* __restrict__ vbuf) {
  const int y = blockIdx.y;
  const int nt = (y == 0) ? ntl[0] : ntl[1];
  const int ti = (y == 0) ? ((int)blockIdx.x >> 2) : ((int)blockIdx.x >> 1);
  const int sub = (y == 0) ? ((int)blockIdx.x & 3) : ((int)blockIdx.x & 1);
  if (ti >= nt) return;
  const int* tt = (y == 0) ? tq : tk;
  const float* x = (y == 0) ? query : (y == 1 ? key : value);
  const __bf16* W = (y == 0) ? Wqt : (y == 1 ? Wkt : Wvt);
  const float* bias = (y == 0) ? bq : (y == 1 ? bk : bv);
  const int* order = (y == 0) ? qorder : korder;
  const int* po = (y == 0) ? pqo : pko;
  __bf16* outp = (y == 0) ? qbuf : (y == 1 ? kbuf : vbuf);
  const float sc = (y == 0) ? 0.36067376f : 1.0f;   // 0.25 * log2(e)

  const int l = tt[2 * ti], prow0 = tt[2 * ti + 1] + sub * 32;
  const int cl = (y == 0) ? cnt[NLBL + l] : cnt[l];
  const int ooff = (y == 0) ? off[10 + l] : off[l];
  const int base = prow0 - po[l];

  const int t = threadIdx.x, w = t >> 6, lane = t & 63;
  const int lr = lane & 15, lk = lane >> 4;

  int src[2];
#pragma unroll
  for (int fi = 0; fi < 2; ++fi) {
    int ridx = base + fi * 16 + lr;
    src[fi] = (ridx < cl) ? order[ooff + ridx] : -1;
  }

  bf16x8 az;
#pragma unroll
  for (int j = 0; j < 8; ++j) az[j] = (__bf16)0.f;

  f32x4 acc[2][4];
#pragma unroll
  for (int i = 0; i < 2; ++i)
#pragma unroll
    for (int j = 0; j < 4; ++j) acc[i][j] = (f32x4){0.f, 0.f, 0.f, 0.f};

  for (int kb = 0; kb < 8; ++kb) {
    const int kbase = kb * 32 + lk * 8;
    bf16x8 a[2], b[4];
#pragma unroll
    for (int fi = 0; fi < 2; ++fi) {
      if (src[fi] >= 0) {
        const float* ap = x + (size_t)src[fi] * D + kbase;
        float4 u0 = *(const float4*)ap;
        float4 u1 = *(const float4*)(ap + 4);
        a[fi] = cvt8(u0, u1);
      } else {
        a[fi] = az;
      }
    }
#pragma unroll
    for (int fj = 0; fj < 4; ++fj) {
      int col = w * 64 + fj * 16 + lr;
      b[fj] = *(const bf16x8*)(W + (size_t)l * 65536 + (size_t)col * D + kbase);
    }
#pragma unroll
    for (int fi = 0; fi < 2; ++fi)
#pragma unroll
      for (int fj = 0; fj < 4; ++fj)
        acc[fi][fj] = __builtin_amdgcn_mfma_f32_16x16x32_bf16(a[fi], b[fj], acc[fi][fj], 0, 0, 0);
  }

#pragma unroll
  for (int fj = 0; fj < 4; ++fj) {
    int col = w * 64 + fj * 16 + lr;
    float bv_ = bias[l * D + col];
#pragma unroll
    for (int fi = 0; fi < 2; ++fi)
#pragma unroll
      for (int r = 0; r < 4; ++r) {
        int row = prow0 + fi * 16 + lk * 4 + r;
        outp[(size_t)row * D + col] = (__bf16)((acc[fi][fj][r] + bv_) * sc);
      }
  }
}

// ---------------------------------------------------------------------------
// Split-K MFMA flash attention, 128-query tiles, no-max softmax, register
// prefetch of next K/V tile (HBM latency hidden under MFMA+softmax).
// Partials stored bf16. grid=(TQ128CAP, H, SPLITK).
// ---------------------------------------------------------------------------
__global__ __launch_bounds__(256) void attn_mfma(
    const __bf16* __restrict__ qbuf, const __bf16* __restrict__ kbuf,
    const __bf16* __restrict__ vbuf, const int* __restrict__ cnt,
    const int* __restrict__ tq, const int* __restrict__ ntl,
    const int* __restrict__ pko,
    __bf16* __restrict__ pctx, float* __restrict__ pstats) {
  const int tqi = blockIdx.x;
  if (tqi >= ntl[0]) return;
  const int l = tq[2 * tqi], prow0 = tq[2 * tqi + 1];
  const int h = blockIdx.y, s = blockIdx.z;
  const int nk = cnt[l];
  const int ntiles = (nk + 63) >> 6;
  const int ntsz = (ntiles + SPLITK - 1) / SPLITK;
  const int tt0 = s * ntsz;
  const int tt1 = min(ntiles, tt0 + ntsz);
  if (tt0 >= tt1) return;

  const int t = threadIdx.x;
  const int w = t >> 6, lane = t & 63;
  const int lr = lane & 15, lk = lane >> 4;

  __shared__ __align__(16) unsigned short ks[4096];    // K tile [key][d]
  __shared__ __align__(16) unsigned short vtl[4096];   // V tile [d][key]
  __shared__ __align__(16) unsigned short plds[8192];  // P [wave][32q][64k]

  const int qbase = prow0 + w * 32;
  bf16x8 b_q[2][2];
#pragma unroll
  for (int qf = 0; qf < 2; ++qf)
#pragma unroll
    for (int kb = 0; kb < 2; ++kb)
      b_q[qf][kb] = *(const bf16x8*)(qbuf + (size_t)(qbase + qf * 16 + lr) * D +
                                     h * DPH + kb * 32 + lk * 8);

  f32x4 acc_o[2][4];
#pragma unroll
  for (int qf = 0; qf < 2; ++qf)
#pragma unroll
    for (int i = 0; i < 4; ++i) acc_o[qf][i] = (f32x4){0.f, 0.f, 0.f, 0.f};
  float lrun[2] = {0.f, 0.f};
  const int kb0 = pko[l];

  // per-thread staging addresses (tile-invariant parts)
  const int krow = t >> 2, kc0 = (t & 3) * 16;
  const __bf16* kptr = kbuf + (size_t)(kb0 + krow) * D + h * DPH + kc0;
  const int vkey2 = (t & 31) * 2, vd0 = (t >> 5) * 8;
  const __bf16* vptr = vbuf + (size_t)(kb0 + vkey2) * D + h * DPH + vd0;

  uint4 kreg0, kreg1;
  u16x8 vreg0, vreg1;
  auto LOADT = [&](int tt) {
    const __bf16* kp = kptr + ((size_t)tt << 6) * D;
    kreg0 = *(const uint4*)kp;
    kreg1 = *(const uint4*)(kp + 8);
    const __bf16* vp = vptr + ((size_t)tt << 6) * D;
    vreg0 = *(const u16x8*)vp;
    vreg1 = *(const u16x8*)(vp + D);
  };

  LOADT(tt0);
  for (int tt = tt0; tt < tt1; ++tt) {
    const int n0 = tt << 6;
    __syncthreads();
    // ---- write staged regs -> swizzled LDS
    *(uint4*)&ks[sw_idx(krow, kc0)] = kreg0;
    *(uint4*)&ks[sw_idx(krow, kc0 + 8)] = kreg1;
#pragma unroll
    for (int j = 0; j < 8; ++j) {
      unsigned int u = (unsigned int)vreg0[j] | ((unsigned int)vreg1[j] << 16);
      *(unsigned int*)&vtl[sw_idx(vd0 + j, vkey2)] = u;
    }
    __syncthreads();
    // ---- prefetch next tile while computing this one
    if (tt + 1 < tt1) LOADT(tt + 1);

    // ---- S^T = K x Q^T : C[key][q], key = fi*16+lk*4+r, q = qf*16+lr
    f32x4 s_acc[2][4];
    const f32x4 zz = {0.f, 0.f, 0.f, 0.f};
#pragma unroll
    for (int fi = 0; fi < 4; ++fi) {
      bf16x8 a0 = *(const bf16x8*)&ks[sw_idx(fi * 16 + lr, lk * 8)];
#pragma unroll
      for (int qf = 0; qf < 2; ++qf)
        s_acc[qf][fi] = __builtin_amdgcn_mfma_f32_16x16x32_bf16(a0, b_q[qf][0], zz, 0, 0, 0);
    }
#pragma unroll
    for (int fi = 0; fi < 4; ++fi) {
      bf16x8 a1 = *(const bf16x8*)&ks[sw_idx(fi * 16 + lr, 32 + lk * 8)];
#pragma unroll
      for (int qf = 0; qf < 2; ++qf)
        s_acc[qf][fi] = __builtin_amdgcn_mfma_f32_16x16x32_bf16(a1, b_q[qf][1], s_acc[qf][fi], 0, 0, 0);
    }

    // ---- softmax weights, no max subtraction (bounded logits, fp32 exp2)
    float p[2][16];
#pragma unroll
    for (int qf = 0; qf < 2; ++qf) {
      float ts = 0.f;
#pragma unroll
      for (int fi = 0; fi < 4; ++fi)
#pragma unroll
        for (int r = 0; r < 4; ++r) {
          int key = n0 + fi * 16 + lk * 4 + r;
          float pv = (key < nk) ? exp2f(s_acc[qf][fi][r]) : 0.f;
          p[qf][fi * 4 + r] = pv;
          ts += pv;
        }
      ts += __shfl_xor(ts, 16, 64);
      ts += __shfl_xor(ts, 32, 64);
      lrun[qf] += ts;
    }

    // ---- P -> per-wave LDS (bf16, swizzled)
#pragma unroll
    for (int qf = 0; qf < 2; ++qf)
#pragma unroll
      for (int fi = 0; fi < 4; ++fi) {
        unsigned int w0 = pk2(p[qf][fi * 4 + 0], p[qf][fi * 4 + 1]);
        unsigned int w1 = pk2(p[qf][fi * 4 + 2], p[qf][fi * 4 + 3]);
        int idx = w * 2048 + sw_idx(qf * 16 + lr, fi * 16 + lk * 4);
        *(uint2*)&plds[idx] = make_uint2(w0, w1);
      }

    // ---- O^T += V^T x P : C[d][q], d = fi*16+lk*4+r
#pragma unroll
    for (int kb = 0; kb < 2; ++kb) {
      bf16x8 bp[2];
#pragma unroll
      for (int qf = 0; qf < 2; ++qf)
        bp[qf] = *(const bf16x8*)&plds[w * 2048 + sw_idx(qf * 16 + lr, kb * 32 + lk * 8)];
#pragma unroll
      for (int fi = 0; fi < 4; ++fi) {
        bf16x8 av = *(const bf16x8*)&vtl[sw_idx(fi * 16 + lr, kb * 32 + lk * 8)];
#pragma unroll
        for (int qf = 0; qf < 2; ++qf)
          acc_o[qf][fi] = __builtin_amdgcn_mfma_f32_16x16x32_bf16(av, bp[qf], acc_o[qf][fi], 0, 0, 0);
      }
    }
  }

  // ---- write partials (bf16)
  const size_t pbase = ((size_t)tqi * H + h) * SPLITK + s;
  __bf16* pc = pctx + pbase * 8192;
#pragma unroll
  for (int qf = 0; qf < 2; ++qf) {
    int qloc = w * 32 + qf * 16 + lr;
#pragma unroll
    for (int fi = 0; fi < 4; ++fi) {
      uint2 u;
      u.x = pk2(acc_o[qf][fi][0], acc_o[qf][fi][1]);
      u.y = pk2(acc_o[qf][fi][2], acc_o[qf][fi][3]);
      *(uint2*)(pc + qloc * 64 + fi * 16 + lk * 4) = u;
    }
    if (lk == 0) pstats[pbase * 128 + qloc] = lrun[qf];
  }
}

// ---------------------------------------------------------------------------
// Fused: merge bf16 split-K partials -> normalized bf16 ctx in LDS -> @Wf
// + bias + residual -> LayerNorm -> scatter to out. grid=(TQ128CAP, 4).
// ---------------------------------------------------------------------------
__global__ __launch_bounds__(256) void proj_ln_kernel(
    const __bf16* __restrict__ pctx, const float* __restrict__ pstats,
    const __bf16* __restrict__ Wft, const float* __restrict__ bf_,
    const float* __restrict__ query,
    const int* __restrict__ qorder, const int* __restrict__ off,
    const int* __restrict__ cnt, const int* __restrict__ pqo,
    const int* __restrict__ tq, const int* __restrict__ ntl,
    const float* __restrict__ gamma, const float* __restrict__ beta,
    float* __restrict__ out) {
  const int tqi = blockIdx.x;
  if (tqi >= ntl[0]) return;
  const int l = tq[2 * tqi];
  const int qq = blockIdx.y;
  const int prow0 = tq[2 * tqi + 1] + qq * 32;
  const int qloc0 = qq * 32;
  const int cl = cnt[NLBL + l];
  const int ooff = off[10 + l];
  const int base = prow0 - pqo[l];
  const int nk = cnt[l];
  const int ntiles = (nk + 63) >> 6;
  const int ntsz = (ntiles + SPLITK - 1) / SPLITK;
  const int nsp = ntiles ? (ntiles + ntsz - 1) / ntsz : 0;

  const int t = threadIdx.x, w = t >> 6, lane = t & 63;
  const int lr = lane & 15, lk = lane >> 4;

  __shared__ int srcs[32];
  __shared__ float linv[32][4];
  __shared__ __align__(16) unsigned short ct[32 * 256];  // merged ctx, swizzled
  __shared__ float psum[4][32], psum2[4][32];
  __shared__ float mu_s[32], is_s[32];

  if (t < 32) {
    int ridx = base + t;
    srcs[t] = (ridx < cl) ? qorder[ooff + ridx] : -1;
  }
  if (t < 128) {
    int row = t >> 2, h = t & 3;
    float L = 0.f;
    for (int s = 0; s < nsp; ++s)
      L += pstats[(((size_t)tqi * H + h) * SPLITK + s) * 128 + qloc0 + row];
    linv[row][h] = (L > 0.f) ? (1.f / L) : 0.f;
  }
  __syncthreads();

  // ---- merge bf16 pctx across splits -> normalized bf16 in ct
  {
    int row = t >> 3, dseg = (t & 7) * 32;
    int h = dseg >> 6, d0 = dseg & 63;
    const __bf16* pb = pctx + (((size_t)tqi * H + h) * SPLITK) * 8192 +
                       (size_t)(qloc0 + row) * 64 + d0;
    float v[32];
#pragma unroll
    for (int j = 0; j < 32; ++j) v[j] = 0.f;
    for (int s = 0; s < nsp; ++s) {
      const __bf16* ps = pb + (size_t)s * 8192;
#pragma unroll
      for (int j4 = 0; j4 < 4; ++j4) {
        u16x8 u = *(const u16x8*)(ps + j4 * 8);
#pragma unroll
        for (int e = 0; e < 8; ++e) v[j4 * 8 + e] += b2f(u[e]);
      }
    }
    float iv = linv[row][h];
    int xr = (row & 7) << 3;
#pragma unroll
    for (int j = 0; j < 32; j += 2)
      *(unsigned int*)&ct[row * 256 + ((dseg + j) ^ xr)] = pk2(v[j] * iv, v[j + 1] * iv);
  }
  __syncthreads();

  // ---- GEMM: res32 = ct @ Wf
  f32x4 acc[2][4];
#pragma unroll
  for (int i = 0; i < 2; ++i)
#pragma unroll
    for (int j = 0; j < 4; ++j) acc[i][j] = (f32x4){0.f, 0.f, 0.f, 0.f};

  for (int kb = 0; kb < 8; ++kb) {
    const int kbase = kb * 32 + lk * 8;
    bf16x8 a[2], b[4];
#pragma unroll
    for (int fi = 0; fi < 2; ++fi) {
      int row = fi * 16 + lr;
      a[fi] = *(const bf16x8*)&ct[row * 256 + (kbase ^ ((row & 7) << 3))];
    }
#pragma unroll
    for (int fj = 0; fj < 4; ++fj) {
      int col = w * 64 + fj * 16 + lr;
      b[fj] = *(const bf16x8*)(Wft + (size_t)col * D + kbase);
    }
#pragma unroll
    for (int fi = 0; fi < 2; ++fi)
#pragma unroll
      for (int fj = 0; fj < 4; ++fj)
        acc[fi][fj] = __builtin_amdgcn_mfma_f32_16x16x32_bf16(a[fi], b[fj], acc[fi][fj], 0, 0, 0);
  }

  float res[2][4][4];
  float s1[2][4], s2[2][4];
#pragma unroll
  for (int fi = 0; fi < 2; ++fi)
#pragma unroll
    for (int r = 0; r < 4; ++r) { s1[fi][r] = 0.f; s2[fi][r] = 0.f; }

#pragma unroll
  for (int fj = 0; fj < 4; ++fj) {
    int col = w * 64 + fj * 16 + lr;
    float bcol = bf_[col];
#pragma unroll
    for (int fi = 0; fi < 2; ++fi)
#pragma unroll
      for (int r = 0; r < 4; ++r) {
        int rowl = fi * 16 + lk * 4 + r;
        int sr = srcs[rowl];
        float qv = (sr >= 0) ? query[(size_t)sr * D + col] : 0.f;
        float v = acc[fi][fj][r] + bcol + qv;
        res[fi][fj][r] = v;
        s1[fi][r] += v;
        s2[fi][r] += v * v;
      }
  }

#pragma unroll
  for (int o2 = 1; o2 <= 8; o2 <<= 1) {
#pragma unroll
    for (int fi = 0; fi < 2; ++fi)
#pragma unroll
      for (int r = 0; r < 4; ++r) {
        s1[fi][r] += __shfl_xor(s1[fi][r], o2, 64);
        s2[fi][r] += __shfl_xor(s2[fi][r], o2, 64);
      }
  }
  if (lr == 0) {
#pragma unroll
    for (int fi = 0; fi < 2; ++fi)
#pragma unroll
      for (int r = 0; r < 4; ++r) {
        int rowl = fi * 16 + lk * 4 + r;
        psum[w][rowl] = s1[fi][r];
        psum2[w][rowl] = s2[fi][r];
      }
  }
  __syncthreads();
  if (t < 32) {
    float tot = psum[0][t] + psum[1][t] + psum[2][t] + psum[3][t];
    float tot2 = psum2[0][t] + psum2[1][t] + psum2[2][t] + psum2[3][t];
    float mu = tot * (1.f / D);
    float var = tot2 * (1.f / D) - mu * mu;
    mu_s[t] = mu;
    is_s[t] = rsqrtf(var + 1e-5f);
  }
  __syncthreads();

#pragma unroll
  for (int fj = 0; fj < 4; ++fj) {
    int col = w * 64 + fj * 16 + lr;
    float gc = gamma[col], bc = beta[col];
#pragma unroll
    for (int fi = 0; fi < 2; ++fi)
#pragma unroll
      for (int r = 0; r < 4; ++r) {
        int rowl = fi * 16 + lk * 4 + r;
        int sr = srcs[rowl];
        if (sr >= 0)
          out[(size_t)sr * D + col] =
              (res[fi][fj][r] - mu_s[rowl]) * is_s[rowl] * gc + bc;
      }
  }
}

// ---------------------------------------------------------------------------
extern "C" void kernel_launch(void* const* d_in, const int* in_sizes, int n_in,
                              void* d_out, int out_size, void* d_ws, size_t ws_size,
                              hipStream_t stream) {
  const float* key   = (const float*)d_in[0];
  const float* value = (const float*)d_in[1];
  const float* query = (const float*)d_in[2];
  const int*   lbl1  = (const int*)d_in[3];
  const int*   lbl2  = (const int*)d_in[4];
  const float* Wq = (const float*)d_in[5];
  const float* bq = (const float*)d_in[6];
  const float* Wk = (const float*)d_in[7];
  const float* bk = (const float*)d_in[8];
  const float* Wv = (const float*)d_in[9];
  const float* bv = (const float*)d_in[10];
  const float* Wf = (const float*)d_in[11];
  const float* bf_ = (const float*)d_in[12];
  const float* gamma = (const float*)d_in[13];
  const float* beta  = (const float*)d_in[14];
  float* out = (float*)d_out;

  const int N = in_sizes[0] / D;
  const int M = in_sizes[2] / D;
  const int MP = M + NLBL * 128;              // query padded rows (128-aligned)
  const int NP = N + NLBL * 64;               // key padded rows (64-aligned)
  const int TQCAP = (M + 127) / 128 + NLBL;   // 128-row query tiles
  const int TKCAP = (N + 63) / 64 + NLBL;     // 64-row key tiles

  int* cnt = (int*)d_ws;
  int* off = cnt + 32;
  int* pqo = off + 32;
  int* pko = pqo + 16;
  int* ntl = pko + 16;
  int* tq  = ntl + 16;
  int* tk  = tq + 2 * TQCAP;
  int* korder = tk + 2 * TKCAP;
  int* qorder = korder + N;
  size_t ihdr = (((size_t)(112 + 2 * TQCAP + 2 * TKCAP + N + M)) * 4 + 255) & ~(size_t)255;

  __bf16* Wqt = (__bf16*)((char*)d_ws + ihdr);
  __bf16* Wkt = Wqt + (size_t)9 * 65536;
  __bf16* Wvt = Wkt + (size_t)9 * 65536;
  __bf16* Wft = Wvt + (size_t)9 * 65536;
  __bf16* qbuf = Wft + 65536;
  __bf16* kbuf = qbuf + (size_t)MP * D;
  __bf16* vbuf = kbuf + (size_t)NP * D;
  __bf16* pctx = vbuf + (size_t)NP * D;                        // TQCAP*H*SPLITK*8192 bf16
  float* pstats = (float*)(pctx + (size_t)TQCAP * H * SPLITK * 8192);  // *128 f32

  prep_kernel<<<19 + 28 * 16, 1024, 0, stream>>>(
      lbl1, N, lbl2, M, Wq, Wk, Wv, Wf, Wqt, Wkt, Wvt, Wft,
      cnt, off, pqo, pko, tq, tk, ntl, korder, qorder);

  int gx = TQCAP * 4 > TKCAP * 2 ? TQCAP * 4 : TKCAP * 2;
  gemm_in_kernel<<<dim3(gx, 3), 256, 0, stream>>>(
      query, key, value, Wqt, Wkt, Wvt, bq, bk, bv,
      qorder, korder, off, cnt, pqo, pko, tq, tk, ntl, qbuf, kbuf, vbuf);

  attn_mfma<<<dim3(TQCAP, H, SPLITK), 256, 0, stream>>>(
      qbuf, kbuf, vbuf, cnt, tq, ntl, pko, pctx, pstats);

  proj_ln_kernel<<<dim3(TQCAP, 4), 256, 0, stream>>>(
      pctx, pstats, Wft, bf_, query, qorder, off, cnt, pqo, tq, ntl,
      gamma, beta, out);
}